// Round 17
// baseline (557.411 us; speedup 1.0000x reference)
//
#include <hip/hip_runtime.h>
#include <hip/hip_bf16.h>
#include <stdint.h>
#include <math.h>

#define T_TOK 8192
#define HID   2048
#define NH    16
#define NKV   8
#define HD    128
#define LSEQ  1024
#define BATCH 8
#define QKV_N 4096
#define KDIM  2048
#define NT64  32          // K-tiles of 64 over KDIM=2048
#define SC2   0.12752039376060341f   // (1/sqrt(128)) * log2(e)

typedef __hip_bfloat16 bf16;
typedef __bf16 bf16x8 __attribute__((ext_vector_type(8)));
typedef float  f32x4  __attribute__((ext_vector_type(4)));

typedef const void __attribute__((address_space(1)))* gas_ptr;
typedef void       __attribute__((address_space(3)))* las_ptr;

__device__ __forceinline__ float b2f(bf16 x) { return __bfloat162float(x); }
__device__ __forceinline__ bf16  f2b(float x) { return __float2bfloat16(x); }
__device__ __forceinline__ unsigned short f2u(float x) {
    union { bf16 b; unsigned short u; } c; c.b = __float2bfloat16(x); return c.u;
}

__device__ __forceinline__ bf16x8 ld16(const void* p) {
    union { uint4 u; bf16x8 v; } c;
    c.u = *reinterpret_cast<const uint4*>(p);
    return c.v;
}

// async 16B/lane global->LDS. lds must be wave-uniform base; HW adds lane*16.
__device__ __forceinline__ void cp16(void* lds, const void* g) {
    __builtin_amdgcn_global_load_lds((gas_ptr)g, (las_ptr)lds, 16, 0, 0);
}

// inline-asm LDS reads (opaque to SIInsertWaitcnts) + explicit fences (rule #18).
#define DSR(dst, base, imm) \
    asm volatile("ds_read_b128 %0, %1 offset:" #imm : "=v"(dst) : "v"(base))
#define SCHEDB() __builtin_amdgcn_sched_barrier(0)
#define LGKM0()  asm volatile("s_waitcnt lgkmcnt(0)")
#define MFMA16(a_, b_, c_) __builtin_amdgcn_mfma_f32_16x16x32_bf16(a_, b_, c_, 0, 0, 0)

// ---------------- batched fp32->bf16 converts + modality map (ONE launch) ----
struct F2BSeg { const float* src; bf16* dst; int n4; };
struct F2BArgs {
    F2BSeg s[9];
    const int* und; const int* gen; int* mod; int nmod;
};

__global__ __launch_bounds__(256) void k_f2ball(F2BArgs A) {
    int seg = blockIdx.y;
    int i = blockIdx.x * blockDim.x + threadIdx.x;
    int stride = gridDim.x * blockDim.x;
    if (seg == 9) {
        for (int j = i; j < A.nmod; j += stride) {
            A.mod[A.und[j]] = 0;
            A.mod[A.gen[j]] = 1;
        }
        return;
    }
    F2BSeg sg = A.s[seg];
    const float4* in4 = (const float4*)sg.src;
    ushort4* out4 = (ushort4*)sg.dst;
    for (int j = i; j < sg.n4; j += stride) {
        float4 v = in4[j];
        ushort4 o;
        o.x = f2u(v.x); o.y = f2u(v.y); o.z = f2u(v.z); o.w = f2u(v.w);
        out4[j] = o;
    }
}

// ---------------- routed GEMM: 4-phase, BK=64, 2x64KB dbuf, 2 barriers/tile --
// EXACT R14/R16 kernel (best verified: QKV 181us, MfmaUtil 34%, VGPR 96).
template<int EPI>
__global__ __launch_bounds__(512)
void k_g201(const bf16* __restrict__ A,
            const bf16* __restrict__ Bw_u, const bf16* __restrict__ Bw_g,
            const int* __restrict__ und, const int* __restrict__ gen,
            const float* __restrict__ bq_u, const float* __restrict__ bk_u,
            const float* __restrict__ bv_u,
            const float* __restrict__ bq_g, const float* __restrict__ bk_g,
            const float* __restrict__ bv_g,
            bf16* __restrict__ outB, float* __restrict__ outF) {
    extern __shared__ char smem[];

    int modg = blockIdx.y;
    const bf16* Bw = modg ? Bw_g : Bw_u;
    const int* idx = modg ? gen : und;
    const float* bq = modg ? bq_g : bq_u;
    const float* bk = modg ? bk_g : bk_u;
    const float* bv = modg ? bv_g : bv_u;

    int gx = gridDim.x;
    int bid = blockIdx.x;
    int sw = (bid & 7) * (gx >> 3) + (bid >> 3);
    int tn = sw >> 4, tm = sw & 15;

    int tid = threadIdx.x;
    int w = tid >> 6, lane = tid & 63;
    int l16 = lane & 15, l4 = lane >> 4;
    int wm = w >> 2, wn = w & 3;

    int swzc = (tid & 3) ^ ((tid >> 3) & 3);
    const bf16* pA[2]; const bf16* pB[2];
#pragma unroll
    for (int j = 0; j < 2; ++j) {
        int row = j * 128 + (tid >> 2);
        pA[j] = A + (size_t)idx[tm * 256 + row] * KDIM + swzc * 8;
        pB[j] = Bw + (size_t)(tn * 256 + row) * KDIM + swzc * 8;
    }

    auto SU = [&](int t, int u, int kh) {
        char* dest = smem + (t & 1) * 65536 + u * 32768 + kh * 16384 + w * 1024;
        const bf16* const* p = u ? pB : pA;
        cp16(dest,        p[0] + t * 64 + kh * 32);
        cp16(dest + 8192, p[1] + t * 64 + kh * 32);
    };

    f32x4 acc[8][4];
#pragma unroll
    for (int m = 0; m < 8; ++m)
#pragma unroll
        for (int n = 0; n < 4; ++n) acc[m][n] = {0.f, 0.f, 0.f, 0.f};

    SU(0, 0, 0); SU(0, 1, 0); SU(0, 0, 1); SU(0, 1, 1);
    SU(1, 0, 0); SU(1, 1, 0);
    SCHEDB();
    asm volatile("s_waitcnt vmcnt(8)");
    __builtin_amdgcn_s_barrier();

    uint32_t cByte = (uint32_t)((l4 ^ ((l16 >> 1) & 3)) << 4);
    uint32_t aBase = (uint32_t)(wm * 128 + l16) * 64 + cByte;
    uint32_t bBase = 32768u + (uint32_t)(wn * 64 + l16) * 64 + cByte;

#define MROW(MI, XV) \
    acc[MI][0] = MFMA16(XV, b0, acc[MI][0]); \
    acc[MI][1] = MFMA16(XV, b1, acc[MI][1]); \
    acc[MI][2] = MFMA16(XV, b2, acc[MI][2]); \
    acc[MI][3] = MFMA16(XV, b3, acc[MI][3]);

#pragma unroll 1
    for (int t = 0; t < NT64; ++t) {
        char* buf = smem + (t & 1) * 65536;
        las_ptr aP = (las_ptr)(buf + aBase);
        las_ptr bP = (las_ptr)(buf + bBase);
        bf16x8 b0, b1, b2, b3, x0, x1, x2, x3;

        // ---- phase 1: kk0, m0-3 (residency via p4(t-1); NO barrier)
        DSR(b0, bP, 0);    DSR(b1, bP, 1024);
        DSR(b2, bP, 2048); DSR(b3, bP, 3072);
        DSR(x0, aP, 0);    DSR(x1, aP, 1024);
        DSR(x2, aP, 2048); DSR(x3, aP, 3072);
        if (t + 1 < NT64) SU(t + 1, 0, 1);
        SCHEDB();
        LGKM0(); SCHEDB();
        __builtin_amdgcn_s_setprio(1);
        MROW(0, x0) MROW(1, x1) MROW(2, x2) MROW(3, x3)
        __builtin_amdgcn_s_setprio(0);
        SCHEDB();

        // ---- phase 2: kk0, m4-7; vmcnt(8)+BARRIER
        DSR(x0, aP, 4096); DSR(x1, aP, 5120);
        DSR(x2, aP, 6144); DSR(x3, aP, 7168);
        if (t + 1 < NT64) SU(t + 1, 1, 1);
        SCHEDB();
        if (t < NT64 - 1) asm volatile("s_waitcnt vmcnt(8)");
        else              asm volatile("s_waitcnt vmcnt(0)");
        __builtin_amdgcn_s_barrier();
        LGKM0(); SCHEDB();
        __builtin_amdgcn_s_setprio(1);
        MROW(4, x0) MROW(5, x1) MROW(6, x2) MROW(7, x3)
        __builtin_amdgcn_s_setprio(0);
        SCHEDB();

        // ---- phase 3: kk1, m0-3 (residency via p2; NO barrier)
        DSR(b0, bP, 16384); DSR(b1, bP, 17408);
        DSR(b2, bP, 18432); DSR(b3, bP, 19456);
        DSR(x0, aP, 16384); DSR(x1, aP, 17408);
        DSR(x2, aP, 18432); DSR(x3, aP, 19456);
        if (t + 2 < NT64) SU(t + 2, 0, 0);
        SCHEDB();
        LGKM0(); SCHEDB();
        __builtin_amdgcn_s_setprio(1);
        MROW(0, x0) MROW(1, x1) MROW(2, x2) MROW(3, x3)
        __builtin_amdgcn_s_setprio(0);
        SCHEDB();

        // ---- phase 4: kk1, m4-7; vmcnt(8)+BARRIER
        DSR(x0, aP, 20480); DSR(x1, aP, 21504);
        DSR(x2, aP, 22528); DSR(x3, aP, 23552);
        if (t + 2 < NT64) SU(t + 2, 1, 0);
        SCHEDB();
        if (t < NT64 - 2)       asm volatile("s_waitcnt vmcnt(8)");
        else if (t == NT64 - 2) asm volatile("s_waitcnt vmcnt(4)");
        else                    asm volatile("s_waitcnt vmcnt(0)");
        __builtin_amdgcn_s_barrier();
        LGKM0(); SCHEDB();
        __builtin_amdgcn_s_setprio(1);
        MROW(4, x0) MROW(5, x1) MROW(6, x2) MROW(7, x3)
        __builtin_amdgcn_s_setprio(0);
        SCHEDB();
    }
#undef MROW

    int rowbase = tm * 256 + wm * 128;
    int colbase = tn * 256 + wn * 64;
#pragma unroll
    for (int m = 0; m < 8; ++m) {
#pragma unroll
        for (int r = 0; r < 4; ++r) {
            int row = rowbase + m * 16 + l4 * 4 + r;
            int token = idx[row];
#pragma unroll
            for (int n = 0; n < 4; ++n) {
                int col = colbase + n * 16 + l16;
                float v = acc[m][n][r];
                if (EPI == 0) {
                    float bias = (col < 2048) ? bq[col]
                               : (col < 3072) ? bk[col - 2048] : bv[col - 3072];
                    outB[(size_t)token * QKV_N + col] = f2b(v + bias);
                } else {
                    outF[(size_t)token * HID + col] = v;
                }
            }
        }
    }
}

// ---------------- per-head RMSNorm + RoPE (Q,K only) -------------------------
__global__ __launch_bounds__(256)
void k_normrope(const bf16* __restrict__ qkv,
                const float* __restrict__ cosT, const float* __restrict__ sinT,
                const int* __restrict__ mod,
                const float* __restrict__ qn_u, const float* __restrict__ qn_g,
                const float* __restrict__ kn_u, const float* __restrict__ kn_g,
                bf16* __restrict__ Qo, bf16* __restrict__ Ko) {
    int t = blockIdx.x;
    int tid = threadIdx.x;
    int w = tid >> 6, lane = tid & 63;
    int m = mod[t];
    int b = t >> 10, pos = t & 1023;
    const bf16* row = qkv + (size_t)t * QKV_N;
    int d0 = 2 * lane, d1 = 2 * lane + 1;
    float c0 = cosT[(size_t)t * HD + d0], c1 = cosT[(size_t)t * HD + d1];
    float s0 = sinT[(size_t)t * HD + d0], s1 = sinT[(size_t)t * HD + d1];
    float sgn = (lane < 32) ? -1.f : 1.f;
    const float* qw = m ? qn_g : qn_u;
    const float* kw = m ? kn_g : kn_u;

    for (int u = w; u < 24; u += 4) {
        float v0 = b2f(row[u * HD + d0]);
        float v1 = b2f(row[u * HD + d1]);
        float ss = v0 * v0 + v1 * v1;
#pragma unroll
        for (int msk = 1; msk < 64; msk <<= 1) ss += __shfl_xor(ss, msk);
        float rs = rsqrtf(ss * (1.0f / HD) + 1e-6f);
        const float* wsc = (u < 16) ? qw : kw;
        float n0 = v0 * rs * wsc[d0], n1 = v1 * rs * wsc[d1];
        float o0 = __shfl_xor(n0, 32), o1 = __shfl_xor(n1, 32);
        float r0 = n0 * c0 + sgn * o0 * s0;
        float r1 = n1 * c1 + sgn * o1 * s1;
        if (u < 16) {
            size_t o = ((size_t)(b * NH + u) * LSEQ + pos) * HD;
            Qo[o + d0] = f2b(r0); Qo[o + d1] = f2b(r1);
        } else {
            size_t o = ((size_t)(b * NKV + (u - 16)) * LSEQ + pos) * HD;
            Ko[o + d0] = f2b(r0); Ko[o + d1] = f2b(r1);
        }
    }
}

// ---------------- V transpose: qkv[t][3072+kv*128+d] -> Vt[b,kv][d][pos] -----
__global__ __launch_bounds__(256)
void k_vt(const bf16* __restrict__ qkv, bf16* __restrict__ Vt) {
    __shared__ bf16 lds[64][72];
    int bk = blockIdx.x;
    int b = bk >> 3, kv = bk & 7;
    int pos0 = blockIdx.y * 64;
    int d0 = blockIdx.z * 64;
    int tid = threadIdx.x;

#pragma unroll
    for (int it = 0; it < 2; ++it) {
        int c = tid + it * 256;
        int row = c >> 3, col8 = (c & 7) * 8;
        const bf16* src = qkv + (size_t)(b * LSEQ + pos0 + row) * QKV_N
                        + 3072 + kv * HD + d0 + col8;
        *reinterpret_cast<uint4*>(&lds[row][col8]) = *reinterpret_cast<const uint4*>(src);
    }
    __syncthreads();

#pragma unroll
    for (int it = 0; it < 2; ++it) {
        int c = tid + it * 256;
        int drow = c & 63, pos8 = (c >> 6) * 8;
        union { unsigned short s[8]; uint4 u; } g;
#pragma unroll
        for (int j = 0; j < 8; ++j)
            g.s[j] = *reinterpret_cast<const unsigned short*>(&lds[pos8 + j][drow]);
        bf16* dst = Vt + ((size_t)bk * HD + d0 + drow) * LSEQ + pos0 + pos8;
        *reinterpret_cast<uint4*>(dst) = g.u;
    }
}

// ---------------- causal GQA flash attention (16 q-rows/wave, 2x TLP) --------
// R17: wave grain halved 32->16 q-rows. 64 rowblocks of 16; wave handles
// rowblk j and 63-j (constant 1040 keys). Grid = B*NH*8 = 1024 blocks x 4
// waves = 4096 waves = 16/CU (4/SIMD), double R16's TLP. Per-wave VGPR
// drops (oacc 32, qf 16) so 4/SIMD fits. K/V stay in global (L2-resident).
__global__ __launch_bounds__(256)
void k_attn(const bf16* __restrict__ Q, const bf16* __restrict__ K,
            const bf16* __restrict__ Vt, bf16* __restrict__ O) {
    int bid = blockIdx.x;
    int p = bid & 7;
    int h = (bid >> 3) & 15;
    int b = bid >> 7;
    int tid = threadIdx.x;
    int w = tid >> 6, lane = tid & 63;
    int l16 = lane & 15, l4 = lane >> 4;
    int j = p * 4 + w;   // 0..31

    const bf16* qhb = Q + (size_t)(b * NH + h) * LSEQ * HD;
    int kv = h >> 1;
    const bf16* kb = K + (size_t)(b * NKV + kv) * LSEQ * HD;
    const bf16* vtb = Vt + (size_t)(b * NKV + kv) * HD * LSEQ;

    __shared__ bf16 Pl[4][16][72];

    f32x4 zero = {0.f, 0.f, 0.f, 0.f};

#pragma unroll 1
    for (int half = 0; half < 2; ++half) {
        int rowblk = half ? (63 - j) : j;
        int q0 = rowblk * 16;
        int kend = q0 + 16;

        bf16x8 qf[4];
#pragma unroll
        for (int c = 0; c < 4; ++c)
            qf[c] = ld16(qhb + (size_t)(q0 + l16) * HD + c * 32 + l4 * 8);

        f32x4 oacc[8];
#pragma unroll
        for (int d = 0; d < 8; ++d) oacc[d] = zero;
        float mr[4], lr[4];
#pragma unroll
        for (int r = 0; r < 4; ++r) { mr[r] = -INFINITY; lr[r] = 0.f; }

#pragma unroll 1
        for (int kt = 0; kt < kend; kt += 64) {
            f32x4 s[4];
#pragma unroll
            for (int kf = 0; kf < 4; ++kf) s[kf] = zero;
#pragma unroll
            for (int c = 0; c < 4; ++c) {
                bf16x8 kf4[4];
#pragma unroll
                for (int kf = 0; kf < 4; ++kf)
                    kf4[kf] = ld16(kb + (size_t)(kt + kf * 16 + l16) * HD + c * 32 + l4 * 8);
#pragma unroll
                for (int kf = 0; kf < 4; ++kf)
                    s[kf] = MFMA16(qf[c], kf4[kf], s[kf]);
            }
#pragma unroll
            for (int r = 0; r < 4; ++r) {
                int qrow = q0 + l4 * 4 + r;
                float sc[4];
                float rm = -1e30f;
#pragma unroll
                for (int kf = 0; kf < 4; ++kf) {
                    int key = kt + kf * 16 + l16;
                    sc[kf] = (key <= qrow) ? s[kf][r] * SC2 : -1e30f;
                    rm = fmaxf(rm, sc[kf]);
                }
#pragma unroll
                for (int msk = 1; msk < 16; msk <<= 1) rm = fmaxf(rm, __shfl_xor(rm, msk));
                float mn = fmaxf(mr[r], rm);
                float corr = exp2f(mr[r] - mn);
                mr[r] = mn;
                float rsum = 0.f;
#pragma unroll
                for (int kf = 0; kf < 4; ++kf) {
                    float pv = exp2f(sc[kf] - mn);
                    rsum += pv;
                    Pl[w][l4 * 4 + r][kf * 16 + l16] = f2b(pv);
                }
#pragma unroll
                for (int msk = 1; msk < 16; msk <<= 1) rsum += __shfl_xor(rsum, msk);
                lr[r] = lr[r] * corr + rsum;
#pragma unroll
                for (int d = 0; d < 8; ++d) oacc[d][r] *= corr;
            }
            bf16x8 pf[2];
#pragma unroll
            for (int ks = 0; ks < 2; ++ks)
                pf[ks] = ld16(&Pl[w][l16][ks * 32 + l4 * 8]);
#pragma unroll
            for (int dt = 0; dt < 8; ++dt) {
#pragma unroll
                for (int ks = 0; ks < 2; ++ks) {
                    bf16x8 vfr = ld16(vtb + (size_t)(dt * 16 + l16) * LSEQ + kt + ks * 32 + l4 * 8);
                    oacc[dt] = MFMA16(pf[ks], vfr, oacc[dt]);
                }
            }
        }

#pragma unroll
        for (int r = 0; r < 4; ++r) lr[r] = 1.0f / lr[r];
        int trow = b * LSEQ + q0;
#pragma unroll
        for (int dt = 0; dt < 8; ++dt)
#pragma unroll
            for (int r = 0; r < 4; ++r) {
                int t = trow + l4 * 4 + r;
                O[(size_t)t * HID + h * HD + dt * 16 + l16] = f2b(oacc[dt][r] * lr[r]);
            }
    }
}

// ---------------- launch -----------------------------------------------------
extern "C" void kernel_launch(void* const* d_in, const int* in_sizes, int n_in,
                              void* d_out, int out_size, void* d_ws, size_t ws_size,
                              hipStream_t stream) {
    const float* x    = (const float*)d_in[0];
    const float* cosT = (const float*)d_in[1];
    const float* sinT = (const float*)d_in[2];
    const int* und = (const int*)d_in[4];
    const int* gen = (const int*)d_in[5];
    const float* Wq_u = (const float*)d_in[6];
    const float* bq_u = (const float*)d_in[7];
    const float* Wk_u = (const float*)d_in[8];
    const float* bk_u = (const float*)d_in[9];
    const float* Wv_u = (const float*)d_in[10];
    const float* bv_u = (const float*)d_in[11];
    const float* Wo_u = (const float*)d_in[12];
    const float* Wq_g = (const float*)d_in[13];
    const float* bq_g = (const float*)d_in[14];
    const float* Wk_g = (const float*)d_in[15];
    const float* bk_g = (const float*)d_in[16];
    const float* Wv_g = (const float*)d_in[17];
    const float* bv_g = (const float*)d_in[18];
    const float* Wo_g = (const float*)d_in[19];
    const float* qn_u = (const float*)d_in[20];
    const float* kn_u = (const float*)d_in[21];
    const float* qn_g = (const float*)d_in[22];
    const float* kn_g = (const float*)d_in[23];
    float* out = (float*)d_out;

    char* ws = (char*)d_ws;
    size_t off = 0;
    auto alloc = [&](size_t bytes) -> void* {
        void* p = ws + off;
        off += (bytes + 255) & ~(size_t)255;
        return p;
    };
    bf16* xb      = (bf16*)alloc((size_t)T_TOK * HID * 2);
    bf16* Wqkv_u  = (bf16*)alloc((size_t)QKV_N * KDIM * 2);
    bf16* Wqkv_g  = (bf16*)alloc((size_t)QKV_N * KDIM * 2);
    bf16* Wob_u   = (bf16*)alloc((size_t)HID * HID * 2);
    bf16* Wob_g   = (bf16*)alloc((size_t)HID * HID * 2);
    int*  mod     = (int*)alloc((size_t)T_TOK * 4);
    bf16* qkv     = (bf16*)alloc((size_t)T_TOK * QKV_N * 2);
    bf16* Qa      = (bf16*)alloc((size_t)BATCH * NH  * LSEQ * HD * 2);
    bf16* Ka      = (bf16*)alloc((size_t)BATCH * NKV * LSEQ * HD * 2);
    bf16* Vt      = (bf16*)alloc((size_t)BATCH * NKV * HD * LSEQ * 2);
    bf16* Ob      = (bf16*)alloc((size_t)T_TOK * HID * 2);
    (void)ws_size; (void)in_sizes; (void)n_in; (void)out_size;

    // allow 128KB dynamic LDS for the GEMM kernels (idempotent, capture-safe)
    (void)hipFuncSetAttribute((const void*)k_g201<0>,
                              hipFuncAttributeMaxDynamicSharedMemorySize, 131072);
    (void)hipFuncSetAttribute((const void*)k_g201<1>,
                              hipFuncAttributeMaxDynamicSharedMemorySize, 131072);

    // batched converts + modality map (single launch)
    F2BArgs fa;
    fa.s[0] = { x,    xb,                  T_TOK * HID / 4 };
    fa.s[1] = { Wq_u, Wqkv_u,              2048 * 2048 / 4 };
    fa.s[2] = { Wk_u, Wqkv_u + 2048 * 2048, 1024 * 2048 / 4 };
    fa.s[3] = { Wv_u, Wqkv_u + 3072 * 2048, 1024 * 2048 / 4 };
    fa.s[4] = { Wq_g, Wqkv_g,              2048 * 2048 / 4 };
    fa.s[5] = { Wk_g, Wqkv_g + 2048 * 2048, 1024 * 2048 / 4 };
    fa.s[6] = { Wv_g, Wqkv_g + 3072 * 2048, 1024 * 2048 / 4 };
    fa.s[7] = { Wo_u, Wob_u,               2048 * 2048 / 4 };
    fa.s[8] = { Wo_g, Wob_g,               2048 * 2048 / 4 };
    fa.und = und; fa.gen = gen; fa.mod = mod; fa.nmod = T_TOK / 2;
    k_f2ball<<<dim3(256, 10), 256, 0, stream>>>(fa);

    // routed QKV projections (M=4096, N=4096, K=2048; both modalities)
    k_g201<0><<<dim3(16 * 16, 2), 512, 131072, stream>>>(
        xb, Wqkv_u, Wqkv_g, und, gen, bq_u, bk_u, bv_u, bq_g, bk_g, bv_g,
        qkv, nullptr);

    // RMS + RoPE (Q,K) and V transpose
    k_normrope<<<T_TOK, 256, 0, stream>>>(qkv, cosT, sinT, mod,
                                          qn_u, qn_g, kn_u, kn_g, Qa, Ka);
    k_vt<<<dim3(BATCH * NKV, LSEQ / 64, HD / 64), 256, 0, stream>>>(qkv, Vt);

    // causal GQA attention (16-row waves, 4096 waves = 2x TLP)
    k_attn<<<BATCH * NH * 8, 256, 0, stream>>>(Qa, Ka, Vt, Ob);

    // routed output projections (M=4096, N=2048, K=2048; both modalities)
    k_g201<1><<<dim3(8 * 16, 2), 512, 131072, stream>>>(
        Ob, Wob_u, Wob_g, und, gen, nullptr, nullptr, nullptr,
        nullptr, nullptr, nullptr, nullptr, out);
}

// Round 18
// 466.393 us; speedup vs baseline: 1.1952x; 1.1952x over previous
//
#include <hip/hip_runtime.h>
#include <hip/hip_bf16.h>
#include <stdint.h>
#include <math.h>

#define T_TOK 8192
#define HID   2048
#define NH    16
#define NKV   8
#define HD    128
#define LSEQ  1024
#define BATCH 8
#define QKV_N 4096
#define KDIM  2048
#define NT64  32          // K-tiles of 64 over KDIM=2048
#define SC2   0.12752039376060341f   // (1/sqrt(128)) * log2(e)

typedef __hip_bfloat16 bf16;
typedef __bf16 bf16x8 __attribute__((ext_vector_type(8)));
typedef float  f32x4  __attribute__((ext_vector_type(4)));

typedef const void __attribute__((address_space(1)))* gas_ptr;
typedef void       __attribute__((address_space(3)))* las_ptr;

__device__ __forceinline__ float b2f(bf16 x) { return __bfloat162float(x); }
__device__ __forceinline__ bf16  f2b(float x) { return __float2bfloat16(x); }
__device__ __forceinline__ unsigned short f2u(float x) {
    union { bf16 b; unsigned short u; } c; c.b = __float2bfloat16(x); return c.u;
}

__device__ __forceinline__ bf16x8 ld16(const void* p) {
    union { uint4 u; bf16x8 v; } c;
    c.u = *reinterpret_cast<const uint4*>(p);
    return c.v;
}

// async 16B/lane global->LDS. lds must be wave-uniform base; HW adds lane*16.
__device__ __forceinline__ void cp16(void* lds, const void* g) {
    __builtin_amdgcn_global_load_lds((gas_ptr)g, (las_ptr)lds, 16, 0, 0);
}

// inline-asm LDS reads (opaque to SIInsertWaitcnts) + explicit fences (rule #18).
#define DSR(dst, base, imm) \
    asm volatile("ds_read_b128 %0, %1 offset:" #imm : "=v"(dst) : "v"(base))
#define SCHEDB() __builtin_amdgcn_sched_barrier(0)
#define LGKM0()  asm volatile("s_waitcnt lgkmcnt(0)")
#define MFMA16(a_, b_, c_) __builtin_amdgcn_mfma_f32_16x16x32_bf16(a_, b_, c_, 0, 0, 0)

// ---------------- batched fp32->bf16 converts + modality map (ONE launch) ----
struct F2BSeg { const float* src; bf16* dst; int n4; };
struct F2BArgs {
    F2BSeg s[9];
    const int* und; const int* gen; int* mod; int nmod;
};

__global__ __launch_bounds__(256) void k_f2ball(F2BArgs A) {
    int seg = blockIdx.y;
    int i = blockIdx.x * blockDim.x + threadIdx.x;
    int stride = gridDim.x * blockDim.x;
    if (seg == 9) {
        for (int j = i; j < A.nmod; j += stride) {
            A.mod[A.und[j]] = 0;
            A.mod[A.gen[j]] = 1;
        }
        return;
    }
    F2BSeg sg = A.s[seg];
    const float4* in4 = (const float4*)sg.src;
    ushort4* out4 = (ushort4*)sg.dst;
    for (int j = i; j < sg.n4; j += stride) {
        float4 v = in4[j];
        ushort4 o;
        o.x = f2u(v.x); o.y = f2u(v.y); o.z = f2u(v.z); o.w = f2u(v.w);
        out4[j] = o;
    }
}

// ---------------- routed GEMM: 4-phase, BK=64, 2x64KB dbuf, 2 barriers/tile --
// EXACT R14/R16 kernel (best verified: QKV 181us, MfmaUtil 34%, VGPR 96).
template<int EPI>
__global__ __launch_bounds__(512)
void k_g201(const bf16* __restrict__ A,
            const bf16* __restrict__ Bw_u, const bf16* __restrict__ Bw_g,
            const int* __restrict__ und, const int* __restrict__ gen,
            const float* __restrict__ bq_u, const float* __restrict__ bk_u,
            const float* __restrict__ bv_u,
            const float* __restrict__ bq_g, const float* __restrict__ bk_g,
            const float* __restrict__ bv_g,
            bf16* __restrict__ outB, float* __restrict__ outF) {
    extern __shared__ char smem[];

    int modg = blockIdx.y;
    const bf16* Bw = modg ? Bw_g : Bw_u;
    const int* idx = modg ? gen : und;
    const float* bq = modg ? bq_g : bq_u;
    const float* bk = modg ? bk_g : bk_u;
    const float* bv = modg ? bv_g : bv_u;

    int gx = gridDim.x;
    int bid = blockIdx.x;
    int sw = (bid & 7) * (gx >> 3) + (bid >> 3);
    int tn = sw >> 4, tm = sw & 15;

    int tid = threadIdx.x;
    int w = tid >> 6, lane = tid & 63;
    int l16 = lane & 15, l4 = lane >> 4;
    int wm = w >> 2, wn = w & 3;

    int swzc = (tid & 3) ^ ((tid >> 3) & 3);
    const bf16* pA[2]; const bf16* pB[2];
#pragma unroll
    for (int j = 0; j < 2; ++j) {
        int row = j * 128 + (tid >> 2);
        pA[j] = A + (size_t)idx[tm * 256 + row] * KDIM + swzc * 8;
        pB[j] = Bw + (size_t)(tn * 256 + row) * KDIM + swzc * 8;
    }

    auto SU = [&](int t, int u, int kh) {
        char* dest = smem + (t & 1) * 65536 + u * 32768 + kh * 16384 + w * 1024;
        const bf16* const* p = u ? pB : pA;
        cp16(dest,        p[0] + t * 64 + kh * 32);
        cp16(dest + 8192, p[1] + t * 64 + kh * 32);
    };

    f32x4 acc[8][4];
#pragma unroll
    for (int m = 0; m < 8; ++m)
#pragma unroll
        for (int n = 0; n < 4; ++n) acc[m][n] = {0.f, 0.f, 0.f, 0.f};

    SU(0, 0, 0); SU(0, 1, 0); SU(0, 0, 1); SU(0, 1, 1);
    SU(1, 0, 0); SU(1, 1, 0);
    SCHEDB();
    asm volatile("s_waitcnt vmcnt(8)");
    __builtin_amdgcn_s_barrier();

    uint32_t cByte = (uint32_t)((l4 ^ ((l16 >> 1) & 3)) << 4);
    uint32_t aBase = (uint32_t)(wm * 128 + l16) * 64 + cByte;
    uint32_t bBase = 32768u + (uint32_t)(wn * 64 + l16) * 64 + cByte;

#define MROW(MI, XV) \
    acc[MI][0] = MFMA16(XV, b0, acc[MI][0]); \
    acc[MI][1] = MFMA16(XV, b1, acc[MI][1]); \
    acc[MI][2] = MFMA16(XV, b2, acc[MI][2]); \
    acc[MI][3] = MFMA16(XV, b3, acc[MI][3]);

#pragma unroll 1
    for (int t = 0; t < NT64; ++t) {
        char* buf = smem + (t & 1) * 65536;
        las_ptr aP = (las_ptr)(buf + aBase);
        las_ptr bP = (las_ptr)(buf + bBase);
        bf16x8 b0, b1, b2, b3, x0, x1, x2, x3;

        // ---- phase 1: kk0, m0-3 (residency via p4(t-1); NO barrier)
        DSR(b0, bP, 0);    DSR(b1, bP, 1024);
        DSR(b2, bP, 2048); DSR(b3, bP, 3072);
        DSR(x0, aP, 0);    DSR(x1, aP, 1024);
        DSR(x2, aP, 2048); DSR(x3, aP, 3072);
        if (t + 1 < NT64) SU(t + 1, 0, 1);
        SCHEDB();
        LGKM0(); SCHEDB();
        __builtin_amdgcn_s_setprio(1);
        MROW(0, x0) MROW(1, x1) MROW(2, x2) MROW(3, x3)
        __builtin_amdgcn_s_setprio(0);
        SCHEDB();

        // ---- phase 2: kk0, m4-7; vmcnt(8)+BARRIER
        DSR(x0, aP, 4096); DSR(x1, aP, 5120);
        DSR(x2, aP, 6144); DSR(x3, aP, 7168);
        if (t + 1 < NT64) SU(t + 1, 1, 1);
        SCHEDB();
        if (t < NT64 - 1) asm volatile("s_waitcnt vmcnt(8)");
        else              asm volatile("s_waitcnt vmcnt(0)");
        __builtin_amdgcn_s_barrier();
        LGKM0(); SCHEDB();
        __builtin_amdgcn_s_setprio(1);
        MROW(4, x0) MROW(5, x1) MROW(6, x2) MROW(7, x3)
        __builtin_amdgcn_s_setprio(0);
        SCHEDB();

        // ---- phase 3: kk1, m0-3 (residency via p2; NO barrier)
        DSR(b0, bP, 16384); DSR(b1, bP, 17408);
        DSR(b2, bP, 18432); DSR(b3, bP, 19456);
        DSR(x0, aP, 16384); DSR(x1, aP, 17408);
        DSR(x2, aP, 18432); DSR(x3, aP, 19456);
        if (t + 2 < NT64) SU(t + 2, 0, 0);
        SCHEDB();
        LGKM0(); SCHEDB();
        __builtin_amdgcn_s_setprio(1);
        MROW(0, x0) MROW(1, x1) MROW(2, x2) MROW(3, x3)
        __builtin_amdgcn_s_setprio(0);
        SCHEDB();

        // ---- phase 4: kk1, m4-7; vmcnt(8)+BARRIER
        DSR(x0, aP, 20480); DSR(x1, aP, 21504);
        DSR(x2, aP, 22528); DSR(x3, aP, 23552);
        if (t + 2 < NT64) SU(t + 2, 1, 0);
        SCHEDB();
        if (t < NT64 - 2)       asm volatile("s_waitcnt vmcnt(8)");
        else if (t == NT64 - 2) asm volatile("s_waitcnt vmcnt(4)");
        else                    asm volatile("s_waitcnt vmcnt(0)");
        __builtin_amdgcn_s_barrier();
        LGKM0(); SCHEDB();
        __builtin_amdgcn_s_setprio(1);
        MROW(4, x0) MROW(5, x1) MROW(6, x2) MROW(7, x3)
        __builtin_amdgcn_s_setprio(0);
        SCHEDB();
    }
#undef MROW

    int rowbase = tm * 256 + wm * 128;
    int colbase = tn * 256 + wn * 64;
#pragma unroll
    for (int m = 0; m < 8; ++m) {
#pragma unroll
        for (int r = 0; r < 4; ++r) {
            int row = rowbase + m * 16 + l4 * 4 + r;
            int token = idx[row];
#pragma unroll
            for (int n = 0; n < 4; ++n) {
                int col = colbase + n * 16 + l16;
                float v = acc[m][n][r];
                if (EPI == 0) {
                    float bias = (col < 2048) ? bq[col]
                               : (col < 3072) ? bk[col - 2048] : bv[col - 3072];
                    outB[(size_t)token * QKV_N + col] = f2b(v + bias);
                } else {
                    outF[(size_t)token * HID + col] = v;
                }
            }
        }
    }
}

// ---------------- per-head RMSNorm + RoPE (Q,K only) -------------------------
__global__ __launch_bounds__(256)
void k_normrope(const bf16* __restrict__ qkv,
                const float* __restrict__ cosT, const float* __restrict__ sinT,
                const int* __restrict__ mod,
                const float* __restrict__ qn_u, const float* __restrict__ qn_g,
                const float* __restrict__ kn_u, const float* __restrict__ kn_g,
                bf16* __restrict__ Qo, bf16* __restrict__ Ko) {
    int t = blockIdx.x;
    int tid = threadIdx.x;
    int w = tid >> 6, lane = tid & 63;
    int m = mod[t];
    int b = t >> 10, pos = t & 1023;
    const bf16* row = qkv + (size_t)t * QKV_N;
    int d0 = 2 * lane, d1 = 2 * lane + 1;
    float c0 = cosT[(size_t)t * HD + d0], c1 = cosT[(size_t)t * HD + d1];
    float s0 = sinT[(size_t)t * HD + d0], s1 = sinT[(size_t)t * HD + d1];
    float sgn = (lane < 32) ? -1.f : 1.f;
    const float* qw = m ? qn_g : qn_u;
    const float* kw = m ? kn_g : kn_u;

    for (int u = w; u < 24; u += 4) {
        float v0 = b2f(row[u * HD + d0]);
        float v1 = b2f(row[u * HD + d1]);
        float ss = v0 * v0 + v1 * v1;
#pragma unroll
        for (int msk = 1; msk < 64; msk <<= 1) ss += __shfl_xor(ss, msk);
        float rs = rsqrtf(ss * (1.0f / HD) + 1e-6f);
        const float* wsc = (u < 16) ? qw : kw;
        float n0 = v0 * rs * wsc[d0], n1 = v1 * rs * wsc[d1];
        float o0 = __shfl_xor(n0, 32), o1 = __shfl_xor(n1, 32);
        float r0 = n0 * c0 + sgn * o0 * s0;
        float r1 = n1 * c1 + sgn * o1 * s1;
        if (u < 16) {
            size_t o = ((size_t)(b * NH + u) * LSEQ + pos) * HD;
            Qo[o + d0] = f2b(r0); Qo[o + d1] = f2b(r1);
        } else {
            size_t o = ((size_t)(b * NKV + (u - 16)) * LSEQ + pos) * HD;
            Ko[o + d0] = f2b(r0); Ko[o + d1] = f2b(r1);
        }
    }
}

// ---------------- V transpose: qkv[t][3072+kv*128+d] -> Vt[b,kv][d][pos] -----
__global__ __launch_bounds__(256)
void k_vt(const bf16* __restrict__ qkv, bf16* __restrict__ Vt) {
    __shared__ bf16 lds[64][72];
    int bk = blockIdx.x;
    int b = bk >> 3, kv = bk & 7;
    int pos0 = blockIdx.y * 64;
    int d0 = blockIdx.z * 64;
    int tid = threadIdx.x;

#pragma unroll
    for (int it = 0; it < 2; ++it) {
        int c = tid + it * 256;
        int row = c >> 3, col8 = (c & 7) * 8;
        const bf16* src = qkv + (size_t)(b * LSEQ + pos0 + row) * QKV_N
                        + 3072 + kv * HD + d0 + col8;
        *reinterpret_cast<uint4*>(&lds[row][col8]) = *reinterpret_cast<const uint4*>(src);
    }
    __syncthreads();

#pragma unroll
    for (int it = 0; it < 2; ++it) {
        int c = tid + it * 256;
        int drow = c & 63, pos8 = (c >> 6) * 8;
        union { unsigned short s[8]; uint4 u; } g;
#pragma unroll
        for (int j = 0; j < 8; ++j)
            g.s[j] = *reinterpret_cast<const unsigned short*>(&lds[pos8 + j][drow]);
        bf16* dst = Vt + ((size_t)bk * HD + d0 + drow) * LSEQ + pos0 + pos8;
        *reinterpret_cast<uint4*>(dst) = g.u;
    }
}

// ---------------- causal GQA flash attention (balanced, 32 q-rows/wave) ------
// EXACT R16 kernel (proven ~105us, VGPR 96). R17's 16-row variant regressed
// (VGPR 136, 2x L2 traffic, 269us) -- reverted.
__global__ __launch_bounds__(256)
void k_attn(const bf16* __restrict__ Q, const bf16* __restrict__ K,
            const bf16* __restrict__ Vt, bf16* __restrict__ O) {
    int bid = blockIdx.x;
    int p = bid & 3;
    int h = (bid >> 2) & 15;
    int b = bid >> 6;
    int tid = threadIdx.x;
    int w = tid >> 6, lane = tid & 63;
    int l16 = lane & 15, l4 = lane >> 4;
    int j = p * 4 + w;

    const bf16* qhb = Q + (size_t)(b * NH + h) * LSEQ * HD;
    int kv = h >> 1;
    const bf16* kb = K + (size_t)(b * NKV + kv) * LSEQ * HD;
    const bf16* vtb = Vt + (size_t)(b * NKV + kv) * HD * LSEQ;

    __shared__ bf16 Pl[4][32][72];

    f32x4 zero = {0.f, 0.f, 0.f, 0.f};

#pragma unroll 1
    for (int half = 0; half < 2; ++half) {
        int rowblk = half ? (31 - j) : j;
        int q0 = rowblk * 32;
        int kend = q0 + 32;

        bf16x8 qf[2][4];
#pragma unroll
        for (int rf = 0; rf < 2; ++rf)
#pragma unroll
            for (int c = 0; c < 4; ++c)
                qf[rf][c] = ld16(qhb + (size_t)(q0 + rf * 16 + l16) * HD + c * 32 + l4 * 8);

        f32x4 oacc[2][8];
#pragma unroll
        for (int rf = 0; rf < 2; ++rf)
#pragma unroll
            for (int d = 0; d < 8; ++d) oacc[rf][d] = zero;
        float mr[2][4], lr[2][4];
#pragma unroll
        for (int rf = 0; rf < 2; ++rf)
#pragma unroll
            for (int r = 0; r < 4; ++r) { mr[rf][r] = -INFINITY; lr[rf][r] = 0.f; }

        for (int kt = 0; kt < kend; kt += 64) {
            f32x4 s[2][4];
#pragma unroll
            for (int rf = 0; rf < 2; ++rf)
#pragma unroll
                for (int kf = 0; kf < 4; ++kf) s[rf][kf] = zero;
#pragma unroll
            for (int c = 0; c < 4; ++c) {
                bf16x8 kf4[4];
#pragma unroll
                for (int kf = 0; kf < 4; ++kf)
                    kf4[kf] = ld16(kb + (size_t)(kt + kf * 16 + l16) * HD + c * 32 + l4 * 8);
#pragma unroll
                for (int rf = 0; rf < 2; ++rf)
#pragma unroll
                    for (int kf = 0; kf < 4; ++kf)
                        s[rf][kf] = MFMA16(qf[rf][c], kf4[kf], s[rf][kf]);
            }
#pragma unroll
            for (int rf = 0; rf < 2; ++rf) {
#pragma unroll
                for (int r = 0; r < 4; ++r) {
                    int qrow = q0 + rf * 16 + l4 * 4 + r;
                    float sc[4];
                    float rm = -1e30f;
#pragma unroll
                    for (int kf = 0; kf < 4; ++kf) {
                        int key = kt + kf * 16 + l16;
                        sc[kf] = (key <= qrow) ? s[rf][kf][r] * SC2 : -1e30f;
                        rm = fmaxf(rm, sc[kf]);
                    }
#pragma unroll
                    for (int msk = 1; msk < 16; msk <<= 1) rm = fmaxf(rm, __shfl_xor(rm, msk));
                    float mn = fmaxf(mr[rf][r], rm);
                    float corr = exp2f(mr[rf][r] - mn);
                    mr[rf][r] = mn;
                    float rsum = 0.f;
#pragma unroll
                    for (int kf = 0; kf < 4; ++kf) {
                        float pv = exp2f(sc[kf] - mn);
                        rsum += pv;
                        Pl[w][rf * 16 + l4 * 4 + r][kf * 16 + l16] = f2b(pv);
                    }
#pragma unroll
                    for (int msk = 1; msk < 16; msk <<= 1) rsum += __shfl_xor(rsum, msk);
                    lr[rf][r] = lr[rf][r] * corr + rsum;
#pragma unroll
                    for (int d = 0; d < 8; ++d) oacc[rf][d][r] *= corr;
                }
            }
            bf16x8 pf[2][2];
#pragma unroll
            for (int rf = 0; rf < 2; ++rf)
#pragma unroll
                for (int ks = 0; ks < 2; ++ks)
                    pf[rf][ks] = ld16(&Pl[w][rf * 16 + l16][ks * 32 + l4 * 8]);
#pragma unroll
            for (int dt = 0; dt < 8; ++dt) {
#pragma unroll
                for (int ks = 0; ks < 2; ++ks) {
                    bf16x8 vfr = ld16(vtb + (size_t)(dt * 16 + l16) * LSEQ + kt + ks * 32 + l4 * 8);
#pragma unroll
                    for (int rf = 0; rf < 2; ++rf)
                        oacc[rf][dt] = MFMA16(pf[rf][ks], vfr, oacc[rf][dt]);
                }
            }
        }

#pragma unroll
        for (int rf = 0; rf < 2; ++rf)
#pragma unroll
            for (int r = 0; r < 4; ++r) lr[rf][r] = 1.0f / lr[rf][r];
        int trow = b * LSEQ + q0;
#pragma unroll
        for (int rf = 0; rf < 2; ++rf)
#pragma unroll
            for (int dt = 0; dt < 8; ++dt)
#pragma unroll
                for (int r = 0; r < 4; ++r) {
                    int t = trow + rf * 16 + l4 * 4 + r;
                    O[(size_t)t * HID + h * HD + dt * 16 + l16] = f2b(oacc[rf][dt][r] * lr[rf][r]);
                }
    }
}

// ---------------- launch -----------------------------------------------------
extern "C" void kernel_launch(void* const* d_in, const int* in_sizes, int n_in,
                              void* d_out, int out_size, void* d_ws, size_t ws_size,
                              hipStream_t stream) {
    const float* x    = (const float*)d_in[0];
    const float* cosT = (const float*)d_in[1];
    const float* sinT = (const float*)d_in[2];
    const int* und = (const int*)d_in[4];
    const int* gen = (const int*)d_in[5];
    const float* Wq_u = (const float*)d_in[6];
    const float* bq_u = (const float*)d_in[7];
    const float* Wk_u = (const float*)d_in[8];
    const float* bk_u = (const float*)d_in[9];
    const float* Wv_u = (const float*)d_in[10];
    const float* bv_u = (const float*)d_in[11];
    const float* Wo_u = (const float*)d_in[12];
    const float* Wq_g = (const float*)d_in[13];
    const float* bq_g = (const float*)d_in[14];
    const float* Wk_g = (const float*)d_in[15];
    const float* bk_g = (const float*)d_in[16];
    const float* Wv_g = (const float*)d_in[17];
    const float* bv_g = (const float*)d_in[18];
    const float* Wo_g = (const float*)d_in[19];
    const float* qn_u = (const float*)d_in[20];
    const float* kn_u = (const float*)d_in[21];
    const float* qn_g = (const float*)d_in[22];
    const float* kn_g = (const float*)d_in[23];
    float* out = (float*)d_out;

    char* ws = (char*)d_ws;
    size_t off = 0;
    auto alloc = [&](size_t bytes) -> void* {
        void* p = ws + off;
        off += (bytes + 255) & ~(size_t)255;
        return p;
    };
    bf16* xb      = (bf16*)alloc((size_t)T_TOK * HID * 2);
    bf16* Wqkv_u  = (bf16*)alloc((size_t)QKV_N * KDIM * 2);
    bf16* Wqkv_g  = (bf16*)alloc((size_t)QKV_N * KDIM * 2);
    bf16* Wob_u   = (bf16*)alloc((size_t)HID * HID * 2);
    bf16* Wob_g   = (bf16*)alloc((size_t)HID * HID * 2);
    int*  mod     = (int*)alloc((size_t)T_TOK * 4);
    bf16* qkv     = (bf16*)alloc((size_t)T_TOK * QKV_N * 2);
    bf16* Qa      = (bf16*)alloc((size_t)BATCH * NH  * LSEQ * HD * 2);
    bf16* Ka      = (bf16*)alloc((size_t)BATCH * NKV * LSEQ * HD * 2);
    bf16* Vt      = (bf16*)alloc((size_t)BATCH * NKV * HD * LSEQ * 2);
    bf16* Ob      = (bf16*)alloc((size_t)T_TOK * HID * 2);
    (void)ws_size; (void)in_sizes; (void)n_in; (void)out_size;

    // allow 128KB dynamic LDS for the GEMM kernels (idempotent, capture-safe)
    (void)hipFuncSetAttribute((const void*)k_g201<0>,
                              hipFuncAttributeMaxDynamicSharedMemorySize, 131072);
    (void)hipFuncSetAttribute((const void*)k_g201<1>,
                              hipFuncAttributeMaxDynamicSharedMemorySize, 131072);

    // batched converts + modality map (single launch)
    F2BArgs fa;
    fa.s[0] = { x,    xb,                  T_TOK * HID / 4 };
    fa.s[1] = { Wq_u, Wqkv_u,              2048 * 2048 / 4 };
    fa.s[2] = { Wk_u, Wqkv_u + 2048 * 2048, 1024 * 2048 / 4 };
    fa.s[3] = { Wv_u, Wqkv_u + 3072 * 2048, 1024 * 2048 / 4 };
    fa.s[4] = { Wq_g, Wqkv_g,              2048 * 2048 / 4 };
    fa.s[5] = { Wk_g, Wqkv_g + 2048 * 2048, 1024 * 2048 / 4 };
    fa.s[6] = { Wv_g, Wqkv_g + 3072 * 2048, 1024 * 2048 / 4 };
    fa.s[7] = { Wo_u, Wob_u,               2048 * 2048 / 4 };
    fa.s[8] = { Wo_g, Wob_g,               2048 * 2048 / 4 };
    fa.und = und; fa.gen = gen; fa.mod = mod; fa.nmod = T_TOK / 2;
    k_f2ball<<<dim3(256, 10), 256, 0, stream>>>(fa);

    // routed QKV projections (M=4096, N=4096, K=2048; both modalities)
    k_g201<0><<<dim3(16 * 16, 2), 512, 131072, stream>>>(
        xb, Wqkv_u, Wqkv_g, und, gen, bq_u, bk_u, bv_u, bq_g, bk_g, bv_g,
        qkv, nullptr);

    // RMS + RoPE (Q,K) and V transpose
    k_normrope<<<T_TOK, 256, 0, stream>>>(qkv, cosT, sinT, mod,
                                          qn_u, qn_g, kn_u, kn_g, Qa, Ka);
    k_vt<<<dim3(BATCH * NKV, LSEQ / 64, HD / 64), 256, 0, stream>>>(qkv, Vt);

    // causal GQA attention (balanced pairing: 512 uniform blocks)
    k_attn<<<BATCH * NH * 4, 256, 0, stream>>>(Qa, Ka, Vt, Ob);

    // routed output projections (M=4096, N=2048, K=2048; both modalities)
    k_g201<1><<<dim3(8 * 16, 2), 512, 131072, stream>>>(
        Ob, Wob_u, Wob_g, und, gen, nullptr, nullptr, nullptr,
        nullptr, nullptr, nullptr, nullptr, out);
}

// Round 19
// 460.269 us; speedup vs baseline: 1.2111x; 1.0133x over previous
//
#include <hip/hip_runtime.h>
#include <hip/hip_bf16.h>
#include <stdint.h>
#include <math.h>

#define T_TOK 8192
#define HID   2048
#define NH    16
#define NKV   8
#define HD    128
#define LSEQ  1024
#define BATCH 8
#define QKV_N 4096
#define KDIM  2048
#define NT64  32          // K-tiles of 64 over KDIM=2048
#define SC2   0.12752039376060341f   // (1/sqrt(128)) * log2(e)

typedef __hip_bfloat16 bf16;
typedef __bf16 bf16x8 __attribute__((ext_vector_type(8)));
typedef float  f32x4  __attribute__((ext_vector_type(4)));

typedef const void __attribute__((address_space(1)))* gas_ptr;
typedef void       __attribute__((address_space(3)))* las_ptr;

__device__ __forceinline__ float b2f(bf16 x) { return __bfloat162float(x); }
__device__ __forceinline__ bf16  f2b(float x) { return __float2bfloat16(x); }
__device__ __forceinline__ unsigned short f2u(float x) {
    union { bf16 b; unsigned short u; } c; c.b = __float2bfloat16(x); return c.u;
}

__device__ __forceinline__ bf16x8 ld16(const void* p) {
    union { uint4 u; bf16x8 v; } c;
    c.u = *reinterpret_cast<const uint4*>(p);
    return c.v;
}

// async 16B/lane global->LDS. lds must be wave-uniform base; HW adds lane*16.
__device__ __forceinline__ void cp16(void* lds, const void* g) {
    __builtin_amdgcn_global_load_lds((gas_ptr)g, (las_ptr)lds, 16, 0, 0);
}

// inline-asm LDS reads (opaque to SIInsertWaitcnts) + explicit fences (rule #18).
#define DSR(dst, base, imm) \
    asm volatile("ds_read_b128 %0, %1 offset:" #imm : "=v"(dst) : "v"(base))
#define SCHEDB() __builtin_amdgcn_sched_barrier(0)
#define LGKM0()  asm volatile("s_waitcnt lgkmcnt(0)")
#define MFMA16(a_, b_, c_) __builtin_amdgcn_mfma_f32_16x16x32_bf16(a_, b_, c_, 0, 0, 0)

// ---------------- batched fp32->bf16 converts + modality map (ONE launch) ----
struct F2BSeg { const float* src; bf16* dst; int n4; };
struct F2BArgs {
    F2BSeg s[9];
    const int* und; const int* gen; int* mod; int nmod;
};

__global__ __launch_bounds__(256) void k_f2ball(F2BArgs A) {
    int seg = blockIdx.y;
    int i = blockIdx.x * blockDim.x + threadIdx.x;
    int stride = gridDim.x * blockDim.x;
    if (seg == 9) {
        for (int j = i; j < A.nmod; j += stride) {
            A.mod[A.und[j]] = 0;
            A.mod[A.gen[j]] = 1;
        }
        return;
    }
    F2BSeg sg = A.s[seg];
    const float4* in4 = (const float4*)sg.src;
    ushort4* out4 = (ushort4*)sg.dst;
    for (int j = i; j < sg.n4; j += stride) {
        float4 v = in4[j];
        ushort4 o;
        o.x = f2u(v.x); o.y = f2u(v.y); o.z = f2u(v.z); o.w = f2u(v.w);
        out4[j] = o;
    }
}

// ---------------- routed GEMM: 4-phase, BK=64, 2x64KB dbuf, 2 barriers/tile --
// EXACT R14/R16/R18 kernel (best verified: QKV 181us, MfmaUtil 34%, VGPR 96).
// Structure ceiling notes: 1-barrier/tile needs 3 buffers = 192KB > 160KB LDS;
// phase-merge spills acc (R15); this is the 2-buffer optimum.
template<int EPI>
__global__ __launch_bounds__(512)
void k_g201(const bf16* __restrict__ A,
            const bf16* __restrict__ Bw_u, const bf16* __restrict__ Bw_g,
            const int* __restrict__ und, const int* __restrict__ gen,
            const float* __restrict__ bq_u, const float* __restrict__ bk_u,
            const float* __restrict__ bv_u,
            const float* __restrict__ bq_g, const float* __restrict__ bk_g,
            const float* __restrict__ bv_g,
            bf16* __restrict__ outB, float* __restrict__ outF) {
    extern __shared__ char smem[];

    int modg = blockIdx.y;
    const bf16* Bw = modg ? Bw_g : Bw_u;
    const int* idx = modg ? gen : und;
    const float* bq = modg ? bq_g : bq_u;
    const float* bk = modg ? bk_g : bk_u;
    const float* bv = modg ? bv_g : bv_u;

    int gx = gridDim.x;
    int bid = blockIdx.x;
    int sw = (bid & 7) * (gx >> 3) + (bid >> 3);
    int tn = sw >> 4, tm = sw & 15;

    int tid = threadIdx.x;
    int w = tid >> 6, lane = tid & 63;
    int l16 = lane & 15, l4 = lane >> 4;
    int wm = w >> 2, wn = w & 3;

    int swzc = (tid & 3) ^ ((tid >> 3) & 3);
    const bf16* pA[2]; const bf16* pB[2];
#pragma unroll
    for (int j = 0; j < 2; ++j) {
        int row = j * 128 + (tid >> 2);
        pA[j] = A + (size_t)idx[tm * 256 + row] * KDIM + swzc * 8;
        pB[j] = Bw + (size_t)(tn * 256 + row) * KDIM + swzc * 8;
    }

    auto SU = [&](int t, int u, int kh) {
        char* dest = smem + (t & 1) * 65536 + u * 32768 + kh * 16384 + w * 1024;
        const bf16* const* p = u ? pB : pA;
        cp16(dest,        p[0] + t * 64 + kh * 32);
        cp16(dest + 8192, p[1] + t * 64 + kh * 32);
    };

    f32x4 acc[8][4];
#pragma unroll
    for (int m = 0; m < 8; ++m)
#pragma unroll
        for (int n = 0; n < 4; ++n) acc[m][n] = {0.f, 0.f, 0.f, 0.f};

    SU(0, 0, 0); SU(0, 1, 0); SU(0, 0, 1); SU(0, 1, 1);
    SU(1, 0, 0); SU(1, 1, 0);
    SCHEDB();
    asm volatile("s_waitcnt vmcnt(8)");
    __builtin_amdgcn_s_barrier();

    uint32_t cByte = (uint32_t)((l4 ^ ((l16 >> 1) & 3)) << 4);
    uint32_t aBase = (uint32_t)(wm * 128 + l16) * 64 + cByte;
    uint32_t bBase = 32768u + (uint32_t)(wn * 64 + l16) * 64 + cByte;

#define MROW(MI, XV) \
    acc[MI][0] = MFMA16(XV, b0, acc[MI][0]); \
    acc[MI][1] = MFMA16(XV, b1, acc[MI][1]); \
    acc[MI][2] = MFMA16(XV, b2, acc[MI][2]); \
    acc[MI][3] = MFMA16(XV, b3, acc[MI][3]);

#pragma unroll 1
    for (int t = 0; t < NT64; ++t) {
        char* buf = smem + (t & 1) * 65536;
        las_ptr aP = (las_ptr)(buf + aBase);
        las_ptr bP = (las_ptr)(buf + bBase);
        bf16x8 b0, b1, b2, b3, x0, x1, x2, x3;

        // ---- phase 1: kk0, m0-3 (residency via p4(t-1); NO barrier)
        DSR(b0, bP, 0);    DSR(b1, bP, 1024);
        DSR(b2, bP, 2048); DSR(b3, bP, 3072);
        DSR(x0, aP, 0);    DSR(x1, aP, 1024);
        DSR(x2, aP, 2048); DSR(x3, aP, 3072);
        if (t + 1 < NT64) SU(t + 1, 0, 1);
        SCHEDB();
        LGKM0(); SCHEDB();
        __builtin_amdgcn_s_setprio(1);
        MROW(0, x0) MROW(1, x1) MROW(2, x2) MROW(3, x3)
        __builtin_amdgcn_s_setprio(0);
        SCHEDB();

        // ---- phase 2: kk0, m4-7; vmcnt(8)+BARRIER
        DSR(x0, aP, 4096); DSR(x1, aP, 5120);
        DSR(x2, aP, 6144); DSR(x3, aP, 7168);
        if (t + 1 < NT64) SU(t + 1, 1, 1);
        SCHEDB();
        if (t < NT64 - 1) asm volatile("s_waitcnt vmcnt(8)");
        else              asm volatile("s_waitcnt vmcnt(0)");
        __builtin_amdgcn_s_barrier();
        LGKM0(); SCHEDB();
        __builtin_amdgcn_s_setprio(1);
        MROW(4, x0) MROW(5, x1) MROW(6, x2) MROW(7, x3)
        __builtin_amdgcn_s_setprio(0);
        SCHEDB();

        // ---- phase 3: kk1, m0-3 (residency via p2; NO barrier)
        DSR(b0, bP, 16384); DSR(b1, bP, 17408);
        DSR(b2, bP, 18432); DSR(b3, bP, 19456);
        DSR(x0, aP, 16384); DSR(x1, aP, 17408);
        DSR(x2, aP, 18432); DSR(x3, aP, 19456);
        if (t + 2 < NT64) SU(t + 2, 0, 0);
        SCHEDB();
        LGKM0(); SCHEDB();
        __builtin_amdgcn_s_setprio(1);
        MROW(0, x0) MROW(1, x1) MROW(2, x2) MROW(3, x3)
        __builtin_amdgcn_s_setprio(0);
        SCHEDB();

        // ---- phase 4: kk1, m4-7; vmcnt(8)+BARRIER
        DSR(x0, aP, 20480); DSR(x1, aP, 21504);
        DSR(x2, aP, 22528); DSR(x3, aP, 23552);
        if (t + 2 < NT64) SU(t + 2, 1, 0);
        SCHEDB();
        if (t < NT64 - 2)       asm volatile("s_waitcnt vmcnt(8)");
        else if (t == NT64 - 2) asm volatile("s_waitcnt vmcnt(4)");
        else                    asm volatile("s_waitcnt vmcnt(0)");
        __builtin_amdgcn_s_barrier();
        LGKM0(); SCHEDB();
        __builtin_amdgcn_s_setprio(1);
        MROW(4, x0) MROW(5, x1) MROW(6, x2) MROW(7, x3)
        __builtin_amdgcn_s_setprio(0);
        SCHEDB();
    }
#undef MROW

    int rowbase = tm * 256 + wm * 128;
    int colbase = tn * 256 + wn * 64;
#pragma unroll
    for (int m = 0; m < 8; ++m) {
#pragma unroll
        for (int r = 0; r < 4; ++r) {
            int row = rowbase + m * 16 + l4 * 4 + r;
            int token = idx[row];
#pragma unroll
            for (int n = 0; n < 4; ++n) {
                int col = colbase + n * 16 + l16;
                float v = acc[m][n][r];
                if (EPI == 0) {
                    float bias = (col < 2048) ? bq[col]
                               : (col < 3072) ? bk[col - 2048] : bv[col - 3072];
                    outB[(size_t)token * QKV_N + col] = f2b(v + bias);
                } else {
                    outF[(size_t)token * HID + col] = v;
                }
            }
        }
    }
}

// ---------------- fused: per-head RMSNorm+RoPE (Q,K) AND V transpose ---------
// blocks [0, T_TOK): normrope for token bid.
// blocks [T_TOK, T_TOK+2048): V-transpose tile (bk, pos0, d0).
__global__ __launch_bounds__(256)
void k_normvt(const bf16* __restrict__ qkv,
              const float* __restrict__ cosT, const float* __restrict__ sinT,
              const int* __restrict__ mod,
              const float* __restrict__ qn_u, const float* __restrict__ qn_g,
              const float* __restrict__ kn_u, const float* __restrict__ kn_g,
              bf16* __restrict__ Qo, bf16* __restrict__ Ko,
              bf16* __restrict__ Vt) {
    __shared__ bf16 lds[64][72];
    int bid = blockIdx.x;
    int tid = threadIdx.x;

    if (bid < T_TOK) {
        // ------- RMSNorm + RoPE path -------
        int t = bid;
        int w = tid >> 6, lane = tid & 63;
        int m = mod[t];
        int b = t >> 10, pos = t & 1023;
        const bf16* row = qkv + (size_t)t * QKV_N;
        int d0 = 2 * lane, d1 = 2 * lane + 1;
        float c0 = cosT[(size_t)t * HD + d0], c1 = cosT[(size_t)t * HD + d1];
        float s0 = sinT[(size_t)t * HD + d0], s1 = sinT[(size_t)t * HD + d1];
        float sgn = (lane < 32) ? -1.f : 1.f;
        const float* qw = m ? qn_g : qn_u;
        const float* kw = m ? kn_g : kn_u;

        for (int u = w; u < 24; u += 4) {
            float v0 = b2f(row[u * HD + d0]);
            float v1 = b2f(row[u * HD + d1]);
            float ss = v0 * v0 + v1 * v1;
#pragma unroll
            for (int msk = 1; msk < 64; msk <<= 1) ss += __shfl_xor(ss, msk);
            float rs = rsqrtf(ss * (1.0f / HD) + 1e-6f);
            const float* wsc = (u < 16) ? qw : kw;
            float n0 = v0 * rs * wsc[d0], n1 = v1 * rs * wsc[d1];
            float o0 = __shfl_xor(n0, 32), o1 = __shfl_xor(n1, 32);
            float r0 = n0 * c0 + sgn * o0 * s0;
            float r1 = n1 * c1 + sgn * o1 * s1;
            if (u < 16) {
                size_t o = ((size_t)(b * NH + u) * LSEQ + pos) * HD;
                Qo[o + d0] = f2b(r0); Qo[o + d1] = f2b(r1);
            } else {
                size_t o = ((size_t)(b * NKV + (u - 16)) * LSEQ + pos) * HD;
                Ko[o + d0] = f2b(r0); Ko[o + d1] = f2b(r1);
            }
        }
    } else {
        // ------- V transpose path -------
        int v = bid - T_TOK;                // 0..2047
        int bk = v & 63;                    // b*8+kv
        int pos0 = ((v >> 6) & 15) * 64;
        int d0 = (v >> 10) * 64;
        int b = bk >> 3, kv = bk & 7;

#pragma unroll
        for (int it = 0; it < 2; ++it) {
            int c = tid + it * 256;
            int row = c >> 3, col8 = (c & 7) * 8;
            const bf16* src = qkv + (size_t)(b * LSEQ + pos0 + row) * QKV_N
                            + 3072 + kv * HD + d0 + col8;
            *reinterpret_cast<uint4*>(&lds[row][col8]) = *reinterpret_cast<const uint4*>(src);
        }
        __syncthreads();

#pragma unroll
        for (int it = 0; it < 2; ++it) {
            int c = tid + it * 256;
            int drow = c & 63, pos8 = (c >> 6) * 8;
            union { unsigned short s[8]; uint4 u; } g;
#pragma unroll
            for (int j = 0; j < 8; ++j)
                g.s[j] = *reinterpret_cast<const unsigned short*>(&lds[pos8 + j][drow]);
            bf16* dst = Vt + ((size_t)bk * HD + d0 + drow) * LSEQ + pos0 + pos8;
            *reinterpret_cast<uint4*>(dst) = g.u;
        }
    }
}

// ---------------- causal GQA flash attention (balanced, 32 q-rows/wave) ------
// EXACT R16/R18 kernel (proven ~105us, VGPR 96).
__global__ __launch_bounds__(256)
void k_attn(const bf16* __restrict__ Q, const bf16* __restrict__ K,
            const bf16* __restrict__ Vt, bf16* __restrict__ O) {
    int bid = blockIdx.x;
    int p = bid & 3;
    int h = (bid >> 2) & 15;
    int b = bid >> 6;
    int tid = threadIdx.x;
    int w = tid >> 6, lane = tid & 63;
    int l16 = lane & 15, l4 = lane >> 4;
    int j = p * 4 + w;

    const bf16* qhb = Q + (size_t)(b * NH + h) * LSEQ * HD;
    int kv = h >> 1;
    const bf16* kb = K + (size_t)(b * NKV + kv) * LSEQ * HD;
    const bf16* vtb = Vt + (size_t)(b * NKV + kv) * HD * LSEQ;

    __shared__ bf16 Pl[4][32][72];

    f32x4 zero = {0.f, 0.f, 0.f, 0.f};

#pragma unroll 1
    for (int half = 0; half < 2; ++half) {
        int rowblk = half ? (31 - j) : j;
        int q0 = rowblk * 32;
        int kend = q0 + 32;

        bf16x8 qf[2][4];
#pragma unroll
        for (int rf = 0; rf < 2; ++rf)
#pragma unroll
            for (int c = 0; c < 4; ++c)
                qf[rf][c] = ld16(qhb + (size_t)(q0 + rf * 16 + l16) * HD + c * 32 + l4 * 8);

        f32x4 oacc[2][8];
#pragma unroll
        for (int rf = 0; rf < 2; ++rf)
#pragma unroll
            for (int d = 0; d < 8; ++d) oacc[rf][d] = zero;
        float mr[2][4], lr[2][4];
#pragma unroll
        for (int rf = 0; rf < 2; ++rf)
#pragma unroll
            for (int r = 0; r < 4; ++r) { mr[rf][r] = -INFINITY; lr[rf][r] = 0.f; }

        for (int kt = 0; kt < kend; kt += 64) {
            f32x4 s[2][4];
#pragma unroll
            for (int rf = 0; rf < 2; ++rf)
#pragma unroll
                for (int kf = 0; kf < 4; ++kf) s[rf][kf] = zero;
#pragma unroll
            for (int c = 0; c < 4; ++c) {
                bf16x8 kf4[4];
#pragma unroll
                for (int kf = 0; kf < 4; ++kf)
                    kf4[kf] = ld16(kb + (size_t)(kt + kf * 16 + l16) * HD + c * 32 + l4 * 8);
#pragma unroll
                for (int rf = 0; rf < 2; ++rf)
#pragma unroll
                    for (int kf = 0; kf < 4; ++kf)
                        s[rf][kf] = MFMA16(qf[rf][c], kf4[kf], s[rf][kf]);
            }
#pragma unroll
            for (int rf = 0; rf < 2; ++rf) {
#pragma unroll
                for (int r = 0; r < 4; ++r) {
                    int qrow = q0 + rf * 16 + l4 * 4 + r;
                    float sc[4];
                    float rm = -1e30f;
#pragma unroll
                    for (int kf = 0; kf < 4; ++kf) {
                        int key = kt + kf * 16 + l16;
                        sc[kf] = (key <= qrow) ? s[rf][kf][r] * SC2 : -1e30f;
                        rm = fmaxf(rm, sc[kf]);
                    }
#pragma unroll
                    for (int msk = 1; msk < 16; msk <<= 1) rm = fmaxf(rm, __shfl_xor(rm, msk));
                    float mn = fmaxf(mr[rf][r], rm);
                    float corr = exp2f(mr[rf][r] - mn);
                    mr[rf][r] = mn;
                    float rsum = 0.f;
#pragma unroll
                    for (int kf = 0; kf < 4; ++kf) {
                        float pv = exp2f(sc[kf] - mn);
                        rsum += pv;
                        Pl[w][rf * 16 + l4 * 4 + r][kf * 16 + l16] = f2b(pv);
                    }
#pragma unroll
                    for (int msk = 1; msk < 16; msk <<= 1) rsum += __shfl_xor(rsum, msk);
                    lr[rf][r] = lr[rf][r] * corr + rsum;
#pragma unroll
                    for (int d = 0; d < 8; ++d) oacc[rf][d][r] *= corr;
                }
            }
            bf16x8 pf[2][2];
#pragma unroll
            for (int rf = 0; rf < 2; ++rf)
#pragma unroll
                for (int ks = 0; ks < 2; ++ks)
                    pf[rf][ks] = ld16(&Pl[w][rf * 16 + l16][ks * 32 + l4 * 8]);
#pragma unroll
            for (int dt = 0; dt < 8; ++dt) {
#pragma unroll
                for (int ks = 0; ks < 2; ++ks) {
                    bf16x8 vfr = ld16(vtb + (size_t)(dt * 16 + l16) * LSEQ + kt + ks * 32 + l4 * 8);
#pragma unroll
                    for (int rf = 0; rf < 2; ++rf)
                        oacc[rf][dt] = MFMA16(pf[rf][ks], vfr, oacc[rf][dt]);
                }
            }
        }

#pragma unroll
        for (int rf = 0; rf < 2; ++rf)
#pragma unroll
            for (int r = 0; r < 4; ++r) lr[rf][r] = 1.0f / lr[rf][r];
        int trow = b * LSEQ + q0;
#pragma unroll
        for (int rf = 0; rf < 2; ++rf)
#pragma unroll
            for (int dt = 0; dt < 8; ++dt)
#pragma unroll
                for (int r = 0; r < 4; ++r) {
                    int t = trow + rf * 16 + l4 * 4 + r;
                    O[(size_t)t * HID + h * HD + dt * 16 + l16] = f2b(oacc[rf][dt][r] * lr[rf][r]);
                }
    }
}

// ---------------- launch -----------------------------------------------------
extern "C" void kernel_launch(void* const* d_in, const int* in_sizes, int n_in,
                              void* d_out, int out_size, void* d_ws, size_t ws_size,
                              hipStream_t stream) {
    const float* x    = (const float*)d_in[0];
    const float* cosT = (const float*)d_in[1];
    const float* sinT = (const float*)d_in[2];
    const int* und = (const int*)d_in[4];
    const int* gen = (const int*)d_in[5];
    const float* Wq_u = (const float*)d_in[6];
    const float* bq_u = (const float*)d_in[7];
    const float* Wk_u = (const float*)d_in[8];
    const float* bk_u = (const float*)d_in[9];
    const float* Wv_u = (const float*)d_in[10];
    const float* bv_u = (const float*)d_in[11];
    const float* Wo_u = (const float*)d_in[12];
    const float* Wq_g = (const float*)d_in[13];
    const float* bq_g = (const float*)d_in[14];
    const float* Wk_g = (const float*)d_in[15];
    const float* bk_g = (const float*)d_in[16];
    const float* Wv_g = (const float*)d_in[17];
    const float* bv_g = (const float*)d_in[18];
    const float* Wo_g = (const float*)d_in[19];
    const float* qn_u = (const float*)d_in[20];
    const float* kn_u = (const float*)d_in[21];
    const float* qn_g = (const float*)d_in[22];
    const float* kn_g = (const float*)d_in[23];
    float* out = (float*)d_out;

    char* ws = (char*)d_ws;
    size_t off = 0;
    auto alloc = [&](size_t bytes) -> void* {
        void* p = ws + off;
        off += (bytes + 255) & ~(size_t)255;
        return p;
    };
    bf16* xb      = (bf16*)alloc((size_t)T_TOK * HID * 2);
    bf16* Wqkv_u  = (bf16*)alloc((size_t)QKV_N * KDIM * 2);
    bf16* Wqkv_g  = (bf16*)alloc((size_t)QKV_N * KDIM * 2);
    bf16* Wob_u   = (bf16*)alloc((size_t)HID * HID * 2);
    bf16* Wob_g   = (bf16*)alloc((size_t)HID * HID * 2);
    int*  mod     = (int*)alloc((size_t)T_TOK * 4);
    bf16* qkv     = (bf16*)alloc((size_t)T_TOK * QKV_N * 2);
    bf16* Qa      = (bf16*)alloc((size_t)BATCH * NH  * LSEQ * HD * 2);
    bf16* Ka      = (bf16*)alloc((size_t)BATCH * NKV * LSEQ * HD * 2);
    bf16* Vt      = (bf16*)alloc((size_t)BATCH * NKV * HD * LSEQ * 2);
    bf16* Ob      = (bf16*)alloc((size_t)T_TOK * HID * 2);
    (void)ws_size; (void)in_sizes; (void)n_in; (void)out_size;

    // allow 128KB dynamic LDS for the GEMM kernels (idempotent, capture-safe)
    (void)hipFuncSetAttribute((const void*)k_g201<0>,
                              hipFuncAttributeMaxDynamicSharedMemorySize, 131072);
    (void)hipFuncSetAttribute((const void*)k_g201<1>,
                              hipFuncAttributeMaxDynamicSharedMemorySize, 131072);

    // batched converts + modality map (single launch)
    F2BArgs fa;
    fa.s[0] = { x,    xb,                  T_TOK * HID / 4 };
    fa.s[1] = { Wq_u, Wqkv_u,              2048 * 2048 / 4 };
    fa.s[2] = { Wk_u, Wqkv_u + 2048 * 2048, 1024 * 2048 / 4 };
    fa.s[3] = { Wv_u, Wqkv_u + 3072 * 2048, 1024 * 2048 / 4 };
    fa.s[4] = { Wq_g, Wqkv_g,              2048 * 2048 / 4 };
    fa.s[5] = { Wk_g, Wqkv_g + 2048 * 2048, 1024 * 2048 / 4 };
    fa.s[6] = { Wv_g, Wqkv_g + 3072 * 2048, 1024 * 2048 / 4 };
    fa.s[7] = { Wo_u, Wob_u,               2048 * 2048 / 4 };
    fa.s[8] = { Wo_g, Wob_g,               2048 * 2048 / 4 };
    fa.und = und; fa.gen = gen; fa.mod = mod; fa.nmod = T_TOK / 2;
    k_f2ball<<<dim3(256, 10), 256, 0, stream>>>(fa);

    // routed QKV projections (M=4096, N=4096, K=2048; both modalities)
    k_g201<0><<<dim3(16 * 16, 2), 512, 131072, stream>>>(
        xb, Wqkv_u, Wqkv_g, und, gen, bq_u, bk_u, bv_u, bq_g, bk_g, bv_g,
        qkv, nullptr);

    // fused RMS+RoPE (Q,K) + V transpose (single launch)
    k_normvt<<<T_TOK + BATCH * NKV * (LSEQ / 64) * (HD / 64), 256, 0, stream>>>(
        qkv, cosT, sinT, mod, qn_u, qn_g, kn_u, kn_g, Qa, Ka, Vt);

    // causal GQA attention (balanced pairing: 512 uniform blocks)
    k_attn<<<BATCH * NH * 4, 256, 0, stream>>>(Qa, Ka, Vt, Ob);

    // routed output projections (M=4096, N=2048, K=2048; both modalities)
    k_g201<1><<<dim3(8 * 16, 2), 512, 131072, stream>>>(
        Ob, Wob_u, Wob_g, und, gen, nullptr, nullptr, nullptr,
        nullptr, nullptr, nullptr, nullptr, out);
}